// Round 6
// baseline (161.215 us; speedup 1.0000x reference)
//
#include <hip/hip_runtime.h>
#include <math.h>

#define NEGM (-1e30f)

typedef float v2f __attribute__((ext_vector_type(2)));

__device__ __forceinline__ float4 ld4(const float* p) { return *(const float4*)p; }
__device__ __forceinline__ void fma4(float4& a, float s, const float4 w) {
    a.x += s * w.x; a.y += s * w.y; a.z += s * w.z; a.w += s * w.w;
}
__device__ __forceinline__ v2f max0v(v2f a) {
    a.x = fmaxf(a.x, 0.f); a.y = fmaxf(a.y, 0.f); return a;
}

// ---------------- Kernel 1: nested-attention history path ----------------
// One wave per batch row, 4 rows per block (R3 structure, v2f inner loops).
__global__ __launch_bounds__(256) void hist_kernel(
    const float* __restrict__ x_kicks,
    const float* __restrict__ W_ke, const float* __restrict__ b_ke,
    const float* __restrict__ q_inner,
    const float* __restrict__ W_ge, const float* __restrict__ b_ge,
    const float* __restrict__ pos_emb, const float* __restrict__ q_outer,
    const float* __restrict__ log_temp,
    const float* __restrict__ ln_g, const float* __restrict__ ln_b,
    const int* __restrict__ outer_mask, const int* __restrict__ inner_mask,
    float* __restrict__ hist)
{
    __shared__ float s_wke[256];        // W_ke [16][16]
    __shared__ float s_wge[512];        // W_ge [16][32]
    __shared__ float s_qout[256];       // q_outer [8][32]
    __shared__ float s_pg[4][17 * 20];  // per_game, stride 20
    __shared__ float s_enc[4][17 * 36]; // encoded, stride 36
    __shared__ float s_ao[4][136];      // outer scores -> weights

    const int tid  = threadIdx.x;
    const int wid  = tid >> 6;
    const int lane = tid & 63;
    const int b    = blockIdx.x * 4 + wid;

    s_wke[tid] = W_ke[tid];
    s_qout[tid] = q_outer[tid];
    s_wge[tid] = W_ge[tid];
    s_wge[tid + 256] = W_ge[tid + 256];
    __syncthreads();

    float* pg  = s_pg[wid];
    float* enc = s_enc[wid];
    float* ao  = s_ao[wid];

    // ---------- Phase A: kick encoder + inner pool (online softmax) ----------
    if (lane < 51) {
        const float* xb = x_kicks + ((size_t)b * 204 + lane * 4) * 16;
        const int4 msk = *(const int4*)(inner_mask + (size_t)b * 204 + lane * 4);

        v2f qv[8], bk[8];
        #pragma unroll
        for (int j = 0; j < 8; ++j) {
            qv[j] = *(const v2f*)(q_inner + 2 * j);   // uniform -> scalar
            bk[j] = *(const v2f*)(b_ke + 2 * j);
        }

        float m = NEGM, s = 0.f;
        v2f p[8];
        #pragma unroll
        for (int j = 0; j < 8; ++j) p[j] = v2f{0.f, 0.f};

        #pragma unroll
        for (int pp = 0; pp < 4; ++pp) {
            float xs[16];
            {
                float4 x0 = ld4(xb + pp * 16 + 0), x1 = ld4(xb + pp * 16 + 4);
                float4 x2 = ld4(xb + pp * 16 + 8), x3 = ld4(xb + pp * 16 + 12);
                xs[0]=x0.x; xs[1]=x0.y; xs[2]=x0.z; xs[3]=x0.w;
                xs[4]=x1.x; xs[5]=x1.y; xs[6]=x1.z; xs[7]=x1.w;
                xs[8]=x2.x; xs[9]=x2.y; xs[10]=x2.z; xs[11]=x2.w;
                xs[12]=x3.x; xs[13]=x3.y; xs[14]=x3.z; xs[15]=x3.w;
            }
            v2f a[8];
            #pragma unroll
            for (int j = 0; j < 8; ++j) a[j] = bk[j];
            #pragma unroll
            for (int i = 0; i < 16; ++i) {
                v2f xi = {xs[i], xs[i]};
                const v2f* wrow = (const v2f*)&s_wke[i * 16];
                #pragma unroll
                for (int j = 0; j < 8; ++j) a[j] += xi * wrow[j];   // v_pk_fma_f32
            }
            #pragma unroll
            for (int j = 0; j < 8; ++j) a[j] = max0v(a[j]);

            v2f dv = {0.f, 0.f};
            #pragma unroll
            for (int j = 0; j < 8; ++j) dv += a[j] * qv[j];
            float sc = (dv.x + dv.y) * 0.25f;   // DK^-0.5
            int mk = (pp == 0) ? msk.x : (pp == 1) ? msk.y : (pp == 2) ? msk.z : msk.w;

            float scm = mk ? sc : NEGM;
            float mn = fmaxf(m, scm);
            float rm = __expf(m - mn);
            float rw = mk ? __expf(sc - mn) : 0.f;
            s = s * rm + rw;
            v2f rmv = {rm, rm}, rwv = {rw, rw};
            #pragma unroll
            for (int j = 0; j < 8; ++j) p[j] = p[j] * rmv + a[j] * rwv;
            m = mn;
        }

        // 3-lane merge for this game
        const int base = (lane / 3) * 3;
        float gm = fmaxf(fmaxf(__shfl(m, base), __shfl(m, base + 1)), __shfl(m, base + 2));
        float r  = __expf(m - gm);
        float sl = s * r;
        float gs = __shfl(sl, base) + __shfl(sl, base + 1) + __shfl(sl, base + 2);
        float c  = r / gs;                      // kick 0 always valid -> gs > 0
        v2f cv = {c, c};
        #pragma unroll
        for (int j = 0; j < 8; ++j) p[j] *= cv;

        float o[16];
        #pragma unroll
        for (int j = 0; j < 8; ++j) {
            o[2*j]   = __shfl(p[j].x, base) + __shfl(p[j].x, base + 1) + __shfl(p[j].x, base + 2);
            o[2*j+1] = __shfl(p[j].y, base) + __shfl(p[j].y, base + 1) + __shfl(p[j].y, base + 2);
        }
        if (lane == base) {
            const int g = lane / 3;
            *(float4*)&pg[g * 20 + 0]  = make_float4(o[0],  o[1],  o[2],  o[3]);
            *(float4*)&pg[g * 20 + 4]  = make_float4(o[4],  o[5],  o[6],  o[7]);
            *(float4*)&pg[g * 20 + 8]  = make_float4(o[8],  o[9],  o[10], o[11]);
            *(float4*)&pg[g * 20 + 12] = make_float4(o[12], o[13], o[14], o[15]);
        }
    }
    __syncthreads();

    // ---------- Phase B: game encoder + pos emb -> enc[17][32] ----------
    for (int t = lane; t < 136; t += 64) {
        const int g = t >> 3, dq = t & 7;
        float4 acc = ld4(b_ge + dq * 4);
        #pragma unroll
        for (int i = 0; i < 16; ++i) {
            float pv = pg[g * 20 + i];
            fma4(acc, pv, *(float4*)&s_wge[i * 32 + dq * 4]);
        }
        float4 pe = ld4(pos_emb + g * 32 + dq * 4);
        acc.x = fmaxf(acc.x, 0.f) + pe.x; acc.y = fmaxf(acc.y, 0.f) + pe.y;
        acc.z = fmaxf(acc.z, 0.f) + pe.z; acc.w = fmaxf(acc.w, 0.f) + pe.w;
        *(float4*)&enc[g * 36 + dq * 4] = acc;
    }
    __syncthreads();

    // ---------- Phase C: outer attention scores ao[8][17] ----------
    for (int t = lane; t < 136; t += 64) {
        const int q = t / 17, g = t - q * 17;
        float4 acc = {0.f, 0.f, 0.f, 0.f};
        #pragma unroll
        for (int i4 = 0; i4 < 8; ++i4) {
            float4 ev = *(float4*)&enc[g * 36 + i4 * 4];
            float4 qvv = *(float4*)&s_qout[q * 32 + i4 * 4];
            acc.x += ev.x * qvv.x; acc.y += ev.y * qvv.y;
            acc.z += ev.z * qvv.z; acc.w += ev.w * qvv.w;
        }
        float sv = (acc.x + acc.y) + (acc.z + acc.w);
        sv *= 0.17677669529663687f * __expf(-log_temp[q >> 1]);
        ao[t] = outer_mask[b * 17 + g] ? sv : NEGM;
    }
    __syncthreads();

    // ---------- Phase D: outer softmax (8 lanes per query) ----------
    {
        const int q = lane >> 3, j = lane & 7;
        float s0 = ao[q * 17 + j];
        float s1 = ao[q * 17 + j + 8];
        float s2 = (j == 0) ? ao[q * 17 + 16] : NEGM;
        float mx = fmaxf(fmaxf(s0, s1), s2);
        mx = fmaxf(mx, __shfl_xor(mx, 1));
        mx = fmaxf(mx, __shfl_xor(mx, 2));
        mx = fmaxf(mx, __shfl_xor(mx, 4));
        float e0 = __expf(s0 - mx), e1 = __expf(s1 - mx);
        float e2 = (j == 0) ? __expf(s2 - mx) : 0.f;
        float ssum = e0 + e1 + e2;
        ssum += __shfl_xor(ssum, 1);
        ssum += __shfl_xor(ssum, 2);
        ssum += __shfl_xor(ssum, 4);
        float inv = 1.f / ssum;
        ao[q * 17 + j] = e0 * inv;
        ao[q * 17 + j + 8] = e1 * inv;
        if (j == 0) ao[q * 17 + 16] = e2 * inv;
    }
    __syncthreads();

    // ---------- Phase E: pooled + per-target LayerNorm ----------
    {
        const int q = lane >> 3, dq = lane & 7;
        float4 acc = {0.f, 0.f, 0.f, 0.f};
        #pragma unroll
        for (int g = 0; g < 17; ++g) {
            float w = ao[q * 17 + g];
            fma4(acc, w, *(float4*)&enc[g * 36 + dq * 4]);
        }
        float sv = (acc.x + acc.y) + (acc.z + acc.w);
        sv += __shfl_xor(sv, 1); sv += __shfl_xor(sv, 2);
        sv += __shfl_xor(sv, 4); sv += __shfl_xor(sv, 8);
        float mu = sv * 0.015625f;
        float4 d;
        d.x = acc.x - mu; d.y = acc.y - mu; d.z = acc.z - mu; d.w = acc.w - mu;
        float v = (d.x * d.x + d.y * d.y) + (d.z * d.z + d.w * d.w);
        v += __shfl_xor(v, 1); v += __shfl_xor(v, 2);
        v += __shfl_xor(v, 4); v += __shfl_xor(v, 8);
        float rs = rsqrtf(v * 0.015625f + 1e-5f);
        float4 gam = ld4(ln_g + lane * 4);
        float4 bet = ld4(ln_b + lane * 4);
        float4 res;
        res.x = d.x * rs * gam.x + bet.x; res.y = d.y * rs * gam.y + bet.y;
        res.z = d.z * rs * gam.z + bet.z; res.w = d.w * rs * gam.w + bet.w;
        *(float4*)&hist[(size_t)b * 256 + lane * 4] = res;
    }
}

// ---------------- Kernel 2: backbone + per-target heads ----------------
// 16 rows per block, 256 threads. Column-pair (v2f) formulation so the
// weight loads are natural dwordx2 and the FMAs pack to v_pk_fma_f32.
__global__ __launch_bounds__(256) void backbone_kernel(
    const float* __restrict__ x_static,
    const float* __restrict__ W1, const float* __restrict__ b1,
    const float* __restrict__ g1, const float* __restrict__ be1,
    const float* __restrict__ m1, const float* __restrict__ v1,
    const float* __restrict__ W2, const float* __restrict__ b2,
    const float* __restrict__ g2, const float* __restrict__ be2,
    const float* __restrict__ m2, const float* __restrict__ v2,
    const float* __restrict__ Wh1, const float* __restrict__ bh1,
    const float* __restrict__ Wh2, const float* __restrict__ bh2,
    const float* __restrict__ hist, float* __restrict__ out)
{
    __shared__ float s_x[16 * 64];
    __shared__ float s_z1[16 * 256];
    __shared__ float s_z2[16 * 132];

    const int tid = threadIdx.x;
    const int row0 = blockIdx.x * 16;

    *(float4*)&s_x[tid * 4] = ld4(x_static + (size_t)row0 * 64 + tid * 4);
    __syncthreads();

    // ---- z1 = relu(BN1(x @ W1)) : col-pair per thread, 8 rows ----
    {
        const int cp = tid & 127;          // cols 2cp, 2cp+1
        const int r0 = (tid >> 7) * 8;     // rows 0-7 or 8-15
        v2f acc[8];
        #pragma unroll
        for (int r = 0; r < 8; ++r) acc[r] = v2f{0.f, 0.f};
        for (int k4 = 0; k4 < 16; ++k4) {
            float4 xv[8];
            #pragma unroll
            for (int r = 0; r < 8; ++r) xv[r] = *(float4*)&s_x[(r0 + r) * 64 + k4 * 4];
            #pragma unroll
            for (int c = 0; c < 4; ++c) {
                v2f w2 = *(const v2f*)&W1[(k4 * 4 + c) * 256 + 2 * cp];
                #pragma unroll
                for (int r = 0; r < 8; ++r) {
                    float xc = (c == 0) ? xv[r].x : (c == 1) ? xv[r].y : (c == 2) ? xv[r].z : xv[r].w;
                    v2f xb = {xc, xc};
                    acc[r] += xb * w2;
                }
            }
        }
        v2f v1v = *(const v2f*)(v1 + 2 * cp);
        v2f g1v = *(const v2f*)(g1 + 2 * cp);
        v2f b1v = *(const v2f*)(b1 + 2 * cp);
        v2f m1v = *(const v2f*)(m1 + 2 * cp);
        v2f e1v = *(const v2f*)(be1 + 2 * cp);
        v2f scv; scv.x = rsqrtf(v1v.x + 1e-5f) * g1v.x; scv.y = rsqrtf(v1v.y + 1e-5f) * g1v.y;
        v2f offv = b1v - m1v;
        #pragma unroll
        for (int r = 0; r < 8; ++r)
            *(v2f*)&s_z1[(r0 + r) * 256 + 2 * cp] = max0v((acc[r] + offv) * scv + e1v);
    }
    __syncthreads();

    // ---- z2 = relu(BN2(z1 @ W2)) : col-pair per thread, 4 rows ----
    {
        const int cp = tid & 63;           // cols 2cp, 2cp+1
        const int q = tid >> 6;            // rows 4q..4q+3
        v2f acc[4];
        #pragma unroll
        for (int r = 0; r < 4; ++r) acc[r] = v2f{0.f, 0.f};
        for (int k4 = 0; k4 < 64; ++k4) {
            float4 zv[4];
            #pragma unroll
            for (int r = 0; r < 4; ++r) zv[r] = *(float4*)&s_z1[(4 * q + r) * 256 + k4 * 4];
            #pragma unroll
            for (int c = 0; c < 4; ++c) {
                v2f w2 = *(const v2f*)&W2[(k4 * 4 + c) * 128 + 2 * cp];
                #pragma unroll
                for (int r = 0; r < 4; ++r) {
                    float zc = (c == 0) ? zv[r].x : (c == 1) ? zv[r].y : (c == 2) ? zv[r].z : zv[r].w;
                    v2f zb = {zc, zc};
                    acc[r] += zb * w2;
                }
            }
        }
        v2f v2v = *(const v2f*)(v2 + 2 * cp);
        v2f g2v = *(const v2f*)(g2 + 2 * cp);
        v2f b2v = *(const v2f*)(b2 + 2 * cp);
        v2f m2v = *(const v2f*)(m2 + 2 * cp);
        v2f e2v = *(const v2f*)(be2 + 2 * cp);
        v2f scv; scv.x = rsqrtf(v2v.x + 1e-5f) * g2v.x; scv.y = rsqrtf(v2v.y + 1e-5f) * g2v.y;
        v2f offv = b2v - m2v;
        #pragma unroll
        for (int r = 0; r < 4; ++r)
            *(v2f*)&s_z2[(4 * q + r) * 132 + 2 * cp] = max0v((acc[r] + offv) * scv + e2v);
    }
    __syncthreads();

    // ---- heads: 4 lanes per (row,target), 8 hidden units each ----
    {
        const int p = tid >> 2;
        const int gl = tid & 3;
        const int row = p >> 2;
        const int tgt = p & 3;
        const int j0 = gl * 8;

        v2f acc[4];
        #pragma unroll
        for (int j = 0; j < 4; ++j) acc[j] = *(const v2f*)(bh1 + tgt * 32 + j0 + 2 * j);

        const float* w1p = Wh1 + (size_t)tgt * 192 * 32 + j0;
        for (int d4 = 0; d4 < 32; ++d4) {
            float4 zv = *(float4*)&s_z2[row * 132 + d4 * 4];
            #pragma unroll
            for (int c = 0; c < 4; ++c) {
                float v = (c == 0) ? zv.x : (c == 1) ? zv.y : (c == 2) ? zv.z : zv.w;
                v2f vb = {v, v};
                const v2f* wp = (const v2f*)(w1p + (d4 * 4 + c) * 32);
                #pragma unroll
                for (int j = 0; j < 4; ++j) acc[j] += vb * wp[j];
            }
        }
        const float* hp = hist + (size_t)(row0 + row) * 256 + tgt * 64;
        const float* w1q = w1p + 128 * 32;
        for (int d4 = 0; d4 < 16; ++d4) {
            float4 hv = ld4(hp + d4 * 4);
            #pragma unroll
            for (int c = 0; c < 4; ++c) {
                float v = (c == 0) ? hv.x : (c == 1) ? hv.y : (c == 2) ? hv.z : hv.w;
                v2f vb = {v, v};
                const v2f* wp = (const v2f*)(w1q + (d4 * 4 + c) * 32);
                #pragma unroll
                for (int j = 0; j < 4; ++j) acc[j] += vb * wp[j];
            }
        }
        float ps = 0.f;
        #pragma unroll
        for (int j = 0; j < 4; ++j) {
            ps += fmaxf(acc[j].x, 0.f) * Wh2[tgt * 32 + j0 + 2 * j];
            ps += fmaxf(acc[j].y, 0.f) * Wh2[tgt * 32 + j0 + 2 * j + 1];
        }
        ps += __shfl_xor(ps, 1);
        ps += __shfl_xor(ps, 2);
        if (gl == 0) out[(size_t)(row0 + row) * 4 + tgt] = fmaxf(ps + bh2[tgt], 0.f);
    }
}

extern "C" void kernel_launch(void* const* d_in, const int* in_sizes, int n_in,
                              void* d_out, int out_size, void* d_ws, size_t ws_size,
                              hipStream_t stream) {
    const float* x_static = (const float*)d_in[0];
    const float* x_kicks  = (const float*)d_in[1];
    const float* W_ke     = (const float*)d_in[2];
    const float* b_ke     = (const float*)d_in[3];
    const float* q_inner  = (const float*)d_in[4];
    const float* W_ge     = (const float*)d_in[5];
    const float* b_ge     = (const float*)d_in[6];
    const float* pos_emb  = (const float*)d_in[7];
    const float* q_outer  = (const float*)d_in[8];
    const float* log_temp = (const float*)d_in[9];
    const float* ln_g     = (const float*)d_in[10];
    const float* ln_b     = (const float*)d_in[11];
    const float* W1       = (const float*)d_in[12];
    const float* b1       = (const float*)d_in[13];
    const float* g1       = (const float*)d_in[14];
    const float* be1      = (const float*)d_in[15];
    const float* m1       = (const float*)d_in[16];
    const float* v1       = (const float*)d_in[17];
    const float* W2       = (const float*)d_in[18];
    const float* b2       = (const float*)d_in[19];
    const float* g2       = (const float*)d_in[20];
    const float* be2      = (const float*)d_in[21];
    const float* m2       = (const float*)d_in[22];
    const float* v2       = (const float*)d_in[23];
    const float* Wh1      = (const float*)d_in[24];
    const float* bh1      = (const float*)d_in[25];
    const float* Wh2      = (const float*)d_in[26];
    const float* bh2      = (const float*)d_in[27];
    const int* outer_mask = (const int*)d_in[28];
    const int* inner_mask = (const int*)d_in[29];

    float* hist = (float*)d_ws;           // 16384 * 256 floats = 16.8 MB
    float* out  = (float*)d_out;

    hist_kernel<<<16384 / 4, 256, 0, stream>>>(
        x_kicks, W_ke, b_ke, q_inner, W_ge, b_ge, pos_emb, q_outer,
        log_temp, ln_g, ln_b, outer_mask, inner_mask, hist);

    backbone_kernel<<<16384 / 16, 256, 0, stream>>>(
        x_static, W1, b1, g1, be1, m1, v1, W2, b2, g2, be2, m2, v2,
        Wh1, bh1, Wh2, bh2, hist, out);
}